// Round 9
// baseline (182.530 us; speedup 1.0000x reference)
//
#include <hip/hip_runtime.h>
#include <math.h>

// ---------------- problem constants ----------------
constexpr int NFFT  = 256;
constexpr int HOP   = 64;
constexpr int NBIN  = 129;          // rfft bins
constexpr int NB    = 8;            // batch
constexpr int LMIX  = 65536;
constexpr int LAUX  = 262144;
constexpr int TM    = 1025;         // mix frames
constexpr int TA    = 4097;         // aux frames
constexpr int TROWS = 4175;         // aux frames + zero pad (78)
constexpr int HS    = 126;
constexpr int W     = 26;           // windows
constexpr int NJOBS = NB * W;       // 208
constexpr int NVAL  = TM * NBIN;    // 132225 values per (b,w)
constexpr int KMED  = (NVAL - 1) / 2; // 66112
constexpr int CHUNKS = 8;           // blocks per job in sim passes
constexpr int NBA   = 1024;         // pass-A linear bins
constexpr int FPB   = 8;            // frames per stft block
constexpr int MIXBLKS = (TM + FPB - 1) / FPB;     // 129
constexpr int AUXBLKS = (TROWS + FPB - 1) / FPB;  // 522
constexpr int GFPB  = 4;            // frames per gather block
constexpr int GBLKS = (TM + GFPB - 1) / GFPB;     // 257

// ---------------- workspace layout (bytes) ----------------
constexpr size_t MIXN_OFF  = 0;
constexpr size_t MIXN_BYTES = (size_t)NB * TM * NBIN * sizeof(float2);      // 8,462,400
constexpr size_t AUXN_OFF  = MIXN_OFF + MIXN_BYTES;
constexpr size_t AUXN_BYTES = (size_t)NB * TROWS * NBIN * sizeof(float2);   // 34,468,800
constexpr size_t HIST_OFF  = AUXN_OFF + AUXN_BYTES;
constexpr size_t HIST_BYTES = (size_t)NJOBS * CHUNKS * NBA * 4;             // 6,815,744
constexpr size_t CAND_OFF  = HIST_OFF + HIST_BYTES;
constexpr size_t CAND_BYTES = (size_t)NJOBS * NVAL * 4;                     // 110,011,200 (worst case)
constexpr size_t NAN_OFF   = CAND_OFF + CAND_BYTES;                         // per-chunk, plain stores
constexpr size_t NAN_BYTES = (size_t)NJOBS * CHUNKS * 4;                    // 6656
constexpr size_t NCAND_OFF = NAN_OFF + NAN_BYTES;
constexpr size_t KREM_OFF  = NCAND_OFF + 832;
constexpr size_t MED_OFF   = KREM_OFF + 832;
// total ~160 MB < 256 MiB ws

constexpr float TWOPI_N = (float)(-2.0 * 3.14159265358979323846 / 256.0);

__device__ __forceinline__ float2 twiddle(int k) {   // e^{-2*pi*i*k/256}
    float s, c;
    sincosf(TWOPI_N * (float)k, &s, &c);
    return make_float2(c, s);
}

// ---------------- STFT (mix + aux fused), Cooley-Tukey 256 = 16 x 16 ----------------
// X[k] = sum_{s=0..15} dk^s * Y[s][k&15],  dk = e^{-2pi i k/256}
// Y[s][r] = sum_{n2} x[s + 16 n2] * e^{-2pi i r n2/16}
// Writes X/|X| (NaN where |X|=0 or padded row). Block 0 zeroes ncand.
// Grid: 1D, wgid%8 = batch  (XCD pinning: all blocks of a batch share an XCD's L2)
// __launch_bounds__(256, 4): VGPR cap 128 — without it the compiler targets the
// LDS-derived occupancy (7 blk/CU), caps VGPRs at 64 and SPILLS (r8: 394 MB writes).
__global__ void __launch_bounds__(256, 4)
stft_all(const float* __restrict__ mix, const float* __restrict__ aux,
         float2* __restrict__ mixN, float2* __restrict__ auxN,
         unsigned* __restrict__ ncand)
{
    constexpr int NX = 64 * (FPB - 1) + NFFT;   // 704
    __shared__ float  xs[NX];
    __shared__ float2 Yl[FPB][16][16];          // 16 KB
    __shared__ float2 tw256[256];
    __shared__ float2 cis16[16];

    const int tid  = threadIdx.x;
    const int wgid = blockIdx.x;
    const int b    = wgid & 7;
    const int t    = wgid >> 3;
    const bool isMix = t < MIXBLKS;
    const int f0 = (isMix ? t : t - MIXBLKS) * FPB;
    const int L       = isMix ? LMIX : LAUX;
    const int Tframes = isMix ? TM : TA;
    const int Trows   = isMix ? TM : TROWS;
    const float* x    = isMix ? mix : aux;
    float2* out       = isMix ? mixN : auxN;

    if (wgid == 0 && tid < NJOBS) ncand[tid] = 0u;   // stft precedes sim_compact

    // one sincosf per thread; separate 16-entry table for stage B (broadcast reads)
    tw256[tid] = twiddle(tid);
    if (tid < 16) cis16[tid] = twiddle(16 * tid);

    // load the union of this block's frames once (reflect padding)
    for (int i = tid; i < NX; i += 256) {
        int j = f0 * HOP + i - 128;
        if (j < 0) j = -j;
        if (j >= L) j = 2 * L - 2 - j;
        xs[i] = x[(size_t)b * L + j];
    }
    __syncthreads();

    // stage B, frames-inner: one cis16 broadcast read serves all FPB frames
    const int n1 = (tid >> 4) & 15;
    const int r  = tid & 15;
    {
        float reA[FPB], imA[FPB];
        #pragma unroll
        for (int f = 0; f < FPB; ++f) { reA[f] = 0.f; imA[f] = 0.f; }
        int idx = 0;
        #pragma unroll
        for (int n2 = 0; n2 < 16; ++n2) {
            float2 tv = cis16[idx];
            #pragma unroll
            for (int f = 0; f < FPB; ++f) {
                float v = xs[f * HOP + n1 + 16 * n2];
                reA[f] = fmaf(v, tv.x, reA[f]);
                imA[f] = fmaf(v, tv.y, imA[f]);
            }
            idx = (idx + r) & 15;
        }
        #pragma unroll
        for (int f = 0; f < FPB; ++f) Yl[f][n1][r] = make_float2(reA[f], imA[f]);
    }
    __syncthreads();

    const float QNAN = __int_as_float(0x7FC00000);
    auto emit = [&](int fr, int k, float ar, float ai) {
        if (fr >= Trows) return;
        float2 o;
        if (fr < Tframes) {
            float inv = rsqrtf(ar * ar + ai * ai);   // |X|=0 -> NaN, as desired
            o = make_float2(ar * inv, ai * inv);
        } else {
            o = make_float2(QNAN, QNAN);
        }
        out[((size_t)b * Trows + fr) * NBIN + k] = o;
    };

    // stage C: 4 interleaved register-recurrence chains (tasks tid+256c, c=0..3; all < 1032)
    {
        int fc[4], kc[4];
        float tr[4], ti[4], ar[4], ai[4];
        float2 dk[4];
        #pragma unroll
        for (int c = 0; c < 4; ++c) {
            int jj = tid + 256 * c;
            fc[c] = jj / NBIN; kc[c] = jj - fc[c] * NBIN;
            dk[c] = tw256[kc[c]];
            tr[c] = 1.f; ti[c] = 0.f; ar[c] = 0.f; ai[c] = 0.f;
        }
        #pragma unroll
        for (int s = 0; s < 16; ++s) {
            #pragma unroll
            for (int c = 0; c < 4; ++c) {
                float2 y = Yl[fc[c]][s][kc[c] & 15];
                ar[c] = fmaf(tr[c], y.x, ar[c]); ar[c] = fmaf(-ti[c], y.y, ar[c]);
                ai[c] = fmaf(tr[c], y.y, ai[c]); ai[c] = fmaf( ti[c], y.x, ai[c]);
                float nr = tr[c] * dk[c].x - ti[c] * dk[c].y;
                ti[c] = fmaf(tr[c], dk[c].y, ti[c] * dk[c].x);
                tr[c] = nr;
            }
        }
        #pragma unroll
        for (int c = 0; c < 4; ++c) emit(f0 + fc[c], kc[c], ar[c], ai[c]);
    }
    if (tid < FPB * NBIN - 1024) {                 // remainder tasks 1024..1031 (8)
        const int jj = 1024 + tid;
        const int f = jj / NBIN, k = jj - f * NBIN;
        const float2 dk = tw256[k];
        float tr = 1.f, ti = 0.f, ar = 0.f, ai = 0.f;
        #pragma unroll
        for (int s = 0; s < 16; ++s) {
            float2 y = Yl[f][s][k & 15];
            ar = fmaf(tr, y.x, ar); ar = fmaf(-ti, y.y, ar);
            ai = fmaf(tr, y.y, ai); ai = fmaf( ti, y.x, ai);
            float nr = tr * dk.x - ti * dk.y;
            ti = fmaf(tr, dk.y, ti * dk.x); tr = nr;
        }
        emit(f0 + f, k, ar, ai);
    }
}

// ---------------- key helpers ----------------
__device__ __forceinline__ unsigned flip_key(float s) {
    unsigned u = __float_as_uint(s);
    return (u & 0x80000000u) ? ~u : (u | 0x80000000u);
}
// linear quantization of s in [-1,1] to 1024 bins; NaN -> 1023
__device__ __forceinline__ unsigned qbin(float s) {
    if (!(s == s)) return (unsigned)(NBA - 1);
    int bq = (int)floorf(fmaf(s, 512.f, 512.f));
    bq = max(0, min(NBA - 1, bq));
    return (unsigned)bq;
}

// ---------------- parallel rank-find over 256*PER bins held in registers ----------------
template<int PER>
__device__ __forceinline__ void rank_find(const unsigned (&bins)[PER], unsigned target,
                                          unsigned& out_bin, unsigned& out_rem)
{
    __shared__ unsigned wtot[4];
    __shared__ unsigned result[2];
    const int tid  = threadIdx.x;
    const int lane = tid & 63;
    const int wid  = tid >> 6;

    unsigned st = 0;
    #pragma unroll
    for (int i = 0; i < PER; ++i) st += bins[i];

    unsigned inc = st;
    #pragma unroll
    for (int d = 1; d < 64; d <<= 1) {
        unsigned v = __shfl_up(inc, d);
        if (lane >= d) inc += v;
    }
    if (lane == 63) wtot[wid] = inc;
    __syncthreads();

    unsigned wbase = 0;
    for (int wme = 0; wme < wid; ++wme) wbase += wtot[wme];
    unsigned ex = wbase + inc - st;
    if ((ex <= target) && (target < ex + st)) {        // exactly one thread
        unsigned cum = ex;
        #pragma unroll
        for (int i = 0; i < PER; ++i) {
            if (cum + bins[i] > target) {
                result[0] = (unsigned)(tid * PER + i);
                result[1] = target - cum;
                break;
            }
            cum += bins[i];
        }
    }
    __syncthreads();
    out_bin = result[0];
    out_rem = result[1];
}

// ---------------- PASS A: linear-bin histogram + per-chunk NaN count ----------------
// Grid: 1D 1664, wgid%8 = batch (XCD pinning)
__global__ void sim_hist(const float2* __restrict__ mixN, const float2* __restrict__ auxN,
                         unsigned* __restrict__ hist, unsigned* __restrict__ nanCnt)
{
    constexpr int NCOPY   = 4;
    constexpr int HSTRIDE = NBA + 1;
    __shared__ unsigned lh[NCOPY * HSTRIDE];      // 16.4 KB
    __shared__ unsigned bnan;
    const int tid   = threadIdx.x;
    const int wgid  = blockIdx.x;
    const int b     = wgid & 7;
    const int rest  = wgid >> 3;                  // 0..207
    const int w     = rest / CHUNKS;
    const int chunk = rest - w * CHUNKS;
    const int job   = b * W + w;
    unsigned* lhc = lh + ((tid >> 4) & (NCOPY - 1)) * HSTRIDE;

    for (int i = tid; i < NCOPY * HSTRIDE; i += 256) lh[i] = 0;
    if (tid == 0) bnan = 0;
    __syncthreads();

    unsigned localnan = 0;
    const float2* mrow = mixN + (size_t)b * TM * NBIN;
    const float2* arow = auxN + ((size_t)b * TROWS + (size_t)w * HS) * NBIN;

    const int pad = b & 1;                        // both bases share parity -> float4-aligned
    const int lim = pad + ((NVAL - pad) & ~1);

    for (int i = pad + (chunk * 256 + tid) * 2; i < lim; i += CHUNKS * 512) {
        float4 mv = *reinterpret_cast<const float4*>(mrow + i);
        float4 av = *reinterpret_cast<const float4*>(arow + i);
        float s0 = fmaf(mv.x, av.x, mv.y * av.y);
        float s1 = fmaf(mv.z, av.z, mv.w * av.w);
        if (!(s0 == s0)) localnan++;
        if (!(s1 == s1)) localnan++;
        atomicAdd(&lhc[qbin(s0)], 1u);
        atomicAdd(&lhc[qbin(s1)], 1u);
    }
    if (chunk == 0 && tid == 0) {                 // the one leftover scalar element
        int ie = pad ? 0 : NVAL - 1;
        float2 m = mrow[ie];
        float2 a = arow[ie];
        float s = fmaf(m.x, a.x, m.y * a.y);
        if (!(s == s)) localnan++;
        atomicAdd(&lhc[qbin(s)], 1u);
    }
    if (localnan) atomicAdd(&bnan, localnan);
    __syncthreads();

    unsigned* gh = hist + ((size_t)job * CHUNKS + chunk) * NBA;
    for (int i = tid; i < NBA; i += 256)
        gh[i] = lh[i] + lh[HSTRIDE + i] + lh[2 * HSTRIDE + i] + lh[3 * HSTRIDE + i];
    if (tid == 0) nanCnt[job * CHUNKS + chunk] = bnan;   // plain store
}

// ---------------- PASS B: inline scan (stateless) + compact selected-bin keys ----------
// Grid: 1D 1664, wgid%8 = batch (XCD pinning; re-reads come from this XCD's L2)
__global__ void sim_compact(const float2* __restrict__ mixN, const float2* __restrict__ auxN,
                            const unsigned* __restrict__ hist, unsigned* __restrict__ cand,
                            unsigned* __restrict__ ncand, unsigned* __restrict__ krem)
{
    const int tid   = threadIdx.x;
    const int wgid  = blockIdx.x;
    const int b     = wgid & 7;
    const int rest  = wgid >> 3;
    const int w     = rest / CHUNKS;
    const int chunk = rest - w * CHUNKS;
    const int job   = b * W + w;

    // every block recomputes the same {selbin, rem} from the global hist
    unsigned bins[NBA / 256];
    const unsigned* h = hist + (size_t)job * CHUNKS * NBA;
    #pragma unroll
    for (int i = 0; i < NBA / 256; ++i) {
        unsigned v = 0;
        int bin = tid * (NBA / 256) + i;
        #pragma unroll
        for (int c = 0; c < CHUNKS; ++c) v += h[(size_t)c * NBA + bin];
        bins[i] = v;
    }
    unsigned sb, rem;
    rank_find<NBA / 256>(bins, (unsigned)KMED, sb, rem);
    if (chunk == 0 && tid == 0) krem[job] = rem;

    unsigned* candj  = cand + (size_t)job * NVAL;
    unsigned* ncandj = ncand + job;
    const int lane = tid & 63;

    const float2* mrow = mixN + (size_t)b * TM * NBIN;
    const float2* arow = auxN + ((size_t)b * TROWS + (size_t)w * HS) * NBIN;

    const int pad = b & 1;
    const int lim = pad + ((NVAL - pad) & ~1);

    for (int i = pad + (chunk * 256 + tid) * 2; i < lim; i += CHUNKS * 512) {
        float4 mv = *reinterpret_cast<const float4*>(mrow + i);
        float4 av = *reinterpret_cast<const float4*>(arow + i);
        float sv[2];
        sv[0] = fmaf(mv.x, av.x, mv.y * av.y);
        sv[1] = fmaf(mv.z, av.z, mv.w * av.w);
        #pragma unroll
        for (int u = 0; u < 2; ++u) {
            bool pred = (qbin(sv[u]) == sb);
            unsigned long long m = __ballot(pred);
            if (m) {
                int leader = __ffsll(m) - 1;
                unsigned base = 0;
                if (lane == leader) base = atomicAdd(ncandj, (unsigned)__popcll(m));
                base = (unsigned)__shfl((int)base, leader);
                if (pred) candj[base + __popcll(m & ((1ull << lane) - 1ull))] = flip_key(sv[u]);
            }
        }
    }
    if (chunk == 0 && tid == 0) {
        int ie = pad ? 0 : NVAL - 1;
        float2 m = mrow[ie];
        float2 a = arow[ie];
        float s = fmaf(m.x, a.x, m.y * a.y);
        if (qbin(s) == sb) {
            unsigned idx = atomicAdd(ncandj, 1u);
            candj[idx] = flip_key(s);
        }
    }
}

// ---------------- exact rank-select among candidates (3-phase radix, parallel scan) -----
// Grid: 1D 208, wgid%8 = batch (same XCD as cand producer)
__global__ void select_kernel(const unsigned* __restrict__ cand, const unsigned* __restrict__ ncand,
                              const unsigned* __restrict__ krem, const unsigned* __restrict__ nanCnt,
                              float* __restrict__ med)
{
    __shared__ unsigned h[2048];
    const int wgid = blockIdx.x;
    const int job  = (wgid & 7) * W + (wgid >> 3);
    const int tid  = threadIdx.x;
    const unsigned* c = cand + (size_t)job * NVAL;
    const unsigned n = ncand[job];
    unsigned pref = 0, tgt = krem[job];

    for (int ph = 0; ph < 3; ++ph) {
        for (int i = tid; i < 2048; i += 256) h[i] = 0;
        __syncthreads();
        for (unsigned i = tid; i < n; i += 256) {
            unsigned k = c[i];
            if (ph == 0) atomicAdd(&h[k >> 21], 1u);
            else if (ph == 1) { if ((k >> 21) == (pref >> 21)) atomicAdd(&h[(k >> 10) & 2047u], 1u); }
            else { if ((k >> 10) == (pref >> 10)) atomicAdd(&h[k & 1023u], 1u); }
        }
        __syncthreads();

        unsigned bins[8];
        #pragma unroll
        for (int i = 0; i < 8; ++i) bins[i] = h[tid * 8 + i];
        unsigned sb, rem;
        rank_find<8>(bins, tgt, sb, rem);

        if (ph == 0)      pref = sb << 21;
        else if (ph == 1) pref |= sb << 10;
        else              pref |= sb;
        tgt = rem;
        __syncthreads();
    }

    if (tid == 0) {
        unsigned nan = 0;
        #pragma unroll
        for (int c2 = 0; c2 < CHUNKS; ++c2) nan += nanCnt[job * CHUNKS + c2];
        unsigned key = pref;
        unsigned u = (key & 0x80000000u) ? (key ^ 0x80000000u) : ~key;
        med[job] = (nan > 0u) ? -INFINITY : __uint_as_float(u);
    }
}

// ---------------- gather: inline argmax + recompute raw STFT of selected window ---------
// Grid: 1D 2056, wgid%8 = batch
__global__ void gather_stft(const float* __restrict__ x, const float* __restrict__ med,
                            float* __restrict__ out)
{
    constexpr int NX = 64 * (GFPB - 1) + NFFT;
    __shared__ float  xs[NX];
    __shared__ float2 Yl[GFPB][16][16];
    __shared__ float2 tw256[256];
    __shared__ float2 cis16[16];
    __shared__ int sh_best;

    const int tid  = threadIdx.x;
    const int wgid = blockIdx.x;
    const int b    = wgid & 7;
    const int t0   = (wgid >> 3) * GFPB;        // output row base (0..1024)

    if (tid == 0) {                             // inline argmax (first-wins)
        float mx = -INFINITY; int bi = 0;
        for (int w = 0; w < W; ++w) {
            float v = med[b * W + w];
            if (v > mx) { mx = v; bi = w; }
        }
        sh_best = bi;
    }
    tw256[tid] = twiddle(tid);
    if (tid < 16) cis16[tid] = twiddle(16 * tid);
    __syncthreads();

    const int fr0 = sh_best * HS + t0;          // aux frame base

    for (int i = tid; i < NX; i += 256) {
        int j = fr0 * HOP + i - 128;
        if (j < 0) j = -j;
        if (j >= LAUX) j = 2 * LAUX - 2 - j;
        j = max(0, min(LAUX - 1, j));           // safety clamp
        xs[i] = x[(size_t)b * LAUX + j];
    }
    __syncthreads();

    const int n1 = (tid >> 4) & 15;
    const int r  = tid & 15;
    {
        float reA[GFPB], imA[GFPB];
        #pragma unroll
        for (int f = 0; f < GFPB; ++f) { reA[f] = 0.f; imA[f] = 0.f; }
        int idx = 0;
        #pragma unroll
        for (int n2 = 0; n2 < 16; ++n2) {
            float2 tv = cis16[idx];
            #pragma unroll
            for (int f = 0; f < GFPB; ++f) {
                float v = xs[f * HOP + n1 + 16 * n2];
                reA[f] = fmaf(v, tv.x, reA[f]);
                imA[f] = fmaf(v, tv.y, imA[f]);
            }
            idx = (idx + r) & 15;
        }
        #pragma unroll
        for (int f = 0; f < GFPB; ++f) Yl[f][n1][r] = make_float2(reA[f], imA[f]);
    }
    __syncthreads();

    // 2 register-recurrence chains (tasks tid, tid+256; 516 tasks total) + tail
    auto dotask = [&](int jj) {
        const int f = jj / NBIN, k = jj - f * NBIN;
        const int tt = t0 + f;
        if (tt >= TM) return;
        float ar = 0.f, ai = 0.f;
        if (fr0 + f < TA) {                     // padded rows are zero
            const float2 dk = tw256[k];
            float tr = 1.f, ti = 0.f;
            #pragma unroll
            for (int s = 0; s < 16; ++s) {
                float2 y = Yl[f][s][k & 15];
                ar = fmaf(tr, y.x, ar); ar = fmaf(-ti, y.y, ar);
                ai = fmaf(tr, y.y, ai); ai = fmaf( ti, y.x, ai);
                float nr = tr * dk.x - ti * dk.y;
                ti = fmaf(tr, dk.y, ti * dk.x); tr = nr;
            }
        }
        size_t o = (size_t)tt * NBIN + k;
        out[(size_t)(b * 2 + 0) * NVAL + o] = ar;
        out[(size_t)(b * 2 + 1) * NVAL + o] = ai;
    };
    dotask(tid);
    dotask(tid + 256);
    if (tid < GFPB * NBIN - 512) dotask(512 + tid);
}

// ---------------- launch (5 graph nodes) ----------------
extern "C" void kernel_launch(void* const* d_in, const int* in_sizes, int n_in,
                              void* d_out, int out_size, void* d_ws, size_t ws_size,
                              hipStream_t stream)
{
    const float* mix = (const float*)d_in[0];
    const float* aux = (const float*)d_in[1];
    float* out = (float*)d_out;
    char* ws = (char*)d_ws;

    float2*   mixN = (float2*)(ws + MIXN_OFF);
    float2*   auxN = (float2*)(ws + AUXN_OFF);
    unsigned* hist = (unsigned*)(ws + HIST_OFF);
    unsigned* cand = (unsigned*)(ws + CAND_OFF);
    unsigned* nanC = (unsigned*)(ws + NAN_OFF);
    unsigned* ncand= (unsigned*)(ws + NCAND_OFF);
    unsigned* krem = (unsigned*)(ws + KREM_OFF);
    float*    med  = (float*)(ws + MED_OFF);

    stft_all<<<(MIXBLKS + AUXBLKS) * NB, 256, 0, stream>>>(mix, aux, mixN, auxN, ncand);
    sim_hist<<<NJOBS * CHUNKS, 256, 0, stream>>>(mixN, auxN, hist, nanC);
    sim_compact<<<NJOBS * CHUNKS, 256, 0, stream>>>(mixN, auxN, hist, cand, ncand, krem);
    select_kernel<<<NJOBS, 256, 0, stream>>>(cand, ncand, krem, nanC, med);
    gather_stft<<<GBLKS * NB, 256, 0, stream>>>(aux, med, out);
}

// Round 10
// 118.903 us; speedup vs baseline: 1.5351x; 1.5351x over previous
//
#include <hip/hip_runtime.h>
#include <math.h>

// ---------------- problem constants ----------------
constexpr int NFFT  = 256;
constexpr int HOP   = 64;
constexpr int NBIN  = 129;          // rfft bins
constexpr int NB    = 8;            // batch
constexpr int LMIX  = 65536;
constexpr int LAUX  = 262144;
constexpr int TM    = 1025;         // mix frames
constexpr int TA    = 4097;         // aux frames
constexpr int TROWS = 4175;         // aux frames + zero pad (78)
constexpr int HS    = 126;
constexpr int W     = 26;           // windows
constexpr int NJOBS = NB * W;       // 208
constexpr int NVAL  = TM * NBIN;    // 132225 values per (b,w)
constexpr int KMED  = (NVAL - 1) / 2; // 66112
constexpr int CHUNKS = 8;           // blocks per job in sim passes
constexpr int NBA   = 1024;         // pass-A linear bins
constexpr int FPB   = 4;            // frames per stft block (r6-proven register footprint)
constexpr int MIXBLKS = (TM + FPB - 1) / FPB;     // 257
constexpr int AUXBLKS = (TROWS + FPB - 1) / FPB;  // 1044
constexpr int GFPB  = 4;            // frames per gather block
constexpr int GBLKS = (TM + GFPB - 1) / GFPB;     // 257

// ---------------- workspace layout (bytes) ----------------
constexpr size_t MIXN_OFF  = 0;
constexpr size_t MIXN_BYTES = (size_t)NB * TM * NBIN * sizeof(float2);      // 8,462,400
constexpr size_t AUXN_OFF  = MIXN_OFF + MIXN_BYTES;
constexpr size_t AUXN_BYTES = (size_t)NB * TROWS * NBIN * sizeof(float2);   // 34,468,800
constexpr size_t HIST_OFF  = AUXN_OFF + AUXN_BYTES;
constexpr size_t HIST_BYTES = (size_t)NJOBS * CHUNKS * NBA * 4;             // 6,815,744
constexpr size_t CAND_OFF  = HIST_OFF + HIST_BYTES;
constexpr size_t CAND_BYTES = (size_t)NJOBS * NVAL * 4;                     // 110,011,200 (worst case)
constexpr size_t NAN_OFF   = CAND_OFF + CAND_BYTES;                         // per-chunk, plain stores
constexpr size_t NAN_BYTES = (size_t)NJOBS * CHUNKS * 4;                    // 6656
constexpr size_t NCAND_OFF = NAN_OFF + NAN_BYTES;
constexpr size_t KREM_OFF  = NCAND_OFF + 832;
constexpr size_t MED_OFF   = KREM_OFF + 832;
// total ~160 MB < 256 MiB ws

constexpr float TWOPI_N = (float)(-2.0 * 3.14159265358979323846 / 256.0);

__device__ __forceinline__ float2 twiddle(int k) {   // e^{-2*pi*i*k/256}
    float s, c;
    sincosf(TWOPI_N * (float)k, &s, &c);
    return make_float2(c, s);
}

// ---------------- STFT (mix + aux fused), Cooley-Tukey 256 = 16 x 16 ----------------
// X[k] = sum_{s=0..15} dk^s * Y[s][k&15],  dk = e^{-2pi i k/256}
// Y[s][r] = sum_{n2} x[s + 16 n2] * e^{-2pi i r n2/16}
// Writes X/|X| (NaN where |X|=0 or padded row). Block 0 zeroes ncand.
// Grid: 1D, wgid%8 = batch  (XCD pinning: all blocks of a batch share an XCD's L2)
// NOTE r8/r9 post-mortem: FPB=8 + 4 chains spilled to scratch (394 MB writes, 64 VGPR
// cap the compiler would not lift even with __launch_bounds__). FPB=4 + 2 chains is the
// proven no-spill configuration (r6: 56 VGPR, 42 MB writes).
__global__ void stft_all(const float* __restrict__ mix, const float* __restrict__ aux,
                         float2* __restrict__ mixN, float2* __restrict__ auxN,
                         unsigned* __restrict__ ncand)
{
    constexpr int NX = 64 * (FPB - 1) + NFFT;   // 448
    __shared__ float  xs[NX];
    __shared__ float2 Yl[FPB][16][16];          // 8 KB
    __shared__ float2 cis16[16];

    const int tid  = threadIdx.x;
    const int wgid = blockIdx.x;
    const int b    = wgid & 7;
    const int t    = wgid >> 3;
    const bool isMix = t < MIXBLKS;
    const int f0 = (isMix ? t : t - MIXBLKS) * FPB;
    const int L       = isMix ? LMIX : LAUX;
    const int Tframes = isMix ? TM : TA;
    const int Trows   = isMix ? TM : TROWS;
    const float* x    = isMix ? mix : aux;
    float2* out       = isMix ? mixN : auxN;

    if (wgid == 0 && tid < NJOBS) ncand[tid] = 0u;   // stft precedes sim_compact

    if (tid < 16) cis16[tid] = twiddle(16 * tid);

    // load the union of this block's frames once (reflect padding)
    for (int i = tid; i < NX; i += 256) {
        int j = f0 * HOP + i - 128;
        if (j < 0) j = -j;
        if (j >= L) j = 2 * L - 2 - j;
        xs[i] = x[(size_t)b * L + j];
    }
    __syncthreads();

    // stage B, frames-inner: one cis16 broadcast read serves all FPB frames
    const int n1 = (tid >> 4) & 15;
    const int r  = tid & 15;
    {
        float reA[FPB], imA[FPB];
        #pragma unroll
        for (int f = 0; f < FPB; ++f) { reA[f] = 0.f; imA[f] = 0.f; }
        int idx = 0;
        #pragma unroll
        for (int n2 = 0; n2 < 16; ++n2) {
            float2 tv = cis16[idx];
            #pragma unroll
            for (int f = 0; f < FPB; ++f) {
                float v = xs[f * HOP + n1 + 16 * n2];
                reA[f] = fmaf(v, tv.x, reA[f]);
                imA[f] = fmaf(v, tv.y, imA[f]);
            }
            idx = (idx + r) & 15;
        }
        #pragma unroll
        for (int f = 0; f < FPB; ++f) Yl[f][n1][r] = make_float2(reA[f], imA[f]);
    }
    __syncthreads();

    const float QNAN = __int_as_float(0x7FC00000);
    auto emit = [&](int fr, int k, float ar, float ai) {
        if (fr >= Trows) return;
        float2 o;
        if (fr < Tframes) {
            float inv = rsqrtf(ar * ar + ai * ai);   // |X|=0 -> NaN, as desired
            o = make_float2(ar * inv, ai * inv);
        } else {
            o = make_float2(QNAN, QNAN);
        }
        out[((size_t)b * Trows + fr) * NBIN + k] = o;
    };

    // stage C: two interleaved twiddle-recurrence chains (ILP 2, r6-proven codegen)
    {
        const int jjA = tid, jjB = tid + 256;          // jjB in [256,511] < 516 always
        const int fA = jjA / NBIN, kA = jjA - fA * NBIN;
        const int fB = jjB / NBIN, kB = jjB - fB * NBIN;
        const float2 dkA = twiddle(kA);
        const float2 dkB = twiddle(kB);
        float trA = 1.f, tiA = 0.f, arA = 0.f, aiA = 0.f;
        float trB = 1.f, tiB = 0.f, arB = 0.f, aiB = 0.f;
        #pragma unroll
        for (int s = 0; s < 16; ++s) {
            float2 yA = Yl[fA][s][kA & 15];
            float2 yB = Yl[fB][s][kB & 15];
            arA = fmaf(trA, yA.x, arA); arA = fmaf(-tiA, yA.y, arA);
            aiA = fmaf(trA, yA.y, aiA); aiA = fmaf( tiA, yA.x, aiA);
            arB = fmaf(trB, yB.x, arB); arB = fmaf(-tiB, yB.y, arB);
            aiB = fmaf(trB, yB.y, aiB); aiB = fmaf( tiB, yB.x, aiB);
            float nrA = trA * dkA.x - tiA * dkA.y;
            tiA = fmaf(trA, dkA.y, tiA * dkA.x); trA = nrA;
            float nrB = trB * dkB.x - tiB * dkB.y;
            tiB = fmaf(trB, dkB.y, tiB * dkB.x); trB = nrB;
        }
        emit(f0 + fA, kA, arA, aiA);
        emit(f0 + fB, kB, arB, aiB);
    }
    if (tid < FPB * NBIN - 512) {                      // remainder tasks 512..515
        const int jj = 512 + tid;
        const int f = jj / NBIN, k = jj - f * NBIN;
        const float2 dk = twiddle(k);
        float tr = 1.f, ti = 0.f, ar = 0.f, ai = 0.f;
        #pragma unroll
        for (int s = 0; s < 16; ++s) {
            float2 y = Yl[f][s][k & 15];
            ar = fmaf(tr, y.x, ar); ar = fmaf(-ti, y.y, ar);
            ai = fmaf(tr, y.y, ai); ai = fmaf( ti, y.x, ai);
            float nr = tr * dk.x - ti * dk.y;
            ti = fmaf(tr, dk.y, ti * dk.x); tr = nr;
        }
        emit(f0 + f, k, ar, ai);
    }
}

// ---------------- key helpers ----------------
__device__ __forceinline__ unsigned flip_key(float s) {
    unsigned u = __float_as_uint(s);
    return (u & 0x80000000u) ? ~u : (u | 0x80000000u);
}
// linear quantization of s in [-1,1] to 1024 bins; NaN -> 1023
__device__ __forceinline__ unsigned qbin(float s) {
    if (!(s == s)) return (unsigned)(NBA - 1);
    int bq = (int)floorf(fmaf(s, 512.f, 512.f));
    bq = max(0, min(NBA - 1, bq));
    return (unsigned)bq;
}

// ---------------- parallel rank-find over 256*PER bins held in registers ----------------
template<int PER>
__device__ __forceinline__ void rank_find(const unsigned (&bins)[PER], unsigned target,
                                          unsigned& out_bin, unsigned& out_rem)
{
    __shared__ unsigned wtot[4];
    __shared__ unsigned result[2];
    const int tid  = threadIdx.x;
    const int lane = tid & 63;
    const int wid  = tid >> 6;

    unsigned st = 0;
    #pragma unroll
    for (int i = 0; i < PER; ++i) st += bins[i];

    unsigned inc = st;
    #pragma unroll
    for (int d = 1; d < 64; d <<= 1) {
        unsigned v = __shfl_up(inc, d);
        if (lane >= d) inc += v;
    }
    if (lane == 63) wtot[wid] = inc;
    __syncthreads();

    unsigned wbase = 0;
    for (int wme = 0; wme < wid; ++wme) wbase += wtot[wme];
    unsigned ex = wbase + inc - st;
    if ((ex <= target) && (target < ex + st)) {        // exactly one thread
        unsigned cum = ex;
        #pragma unroll
        for (int i = 0; i < PER; ++i) {
            if (cum + bins[i] > target) {
                result[0] = (unsigned)(tid * PER + i);
                result[1] = target - cum;
                break;
            }
            cum += bins[i];
        }
    }
    __syncthreads();
    out_bin = result[0];
    out_rem = result[1];
}

// ---------------- PASS A: linear-bin histogram + per-chunk NaN count ----------------
// Grid: 1D 1664, wgid%8 = batch (XCD pinning)
__global__ void sim_hist(const float2* __restrict__ mixN, const float2* __restrict__ auxN,
                         unsigned* __restrict__ hist, unsigned* __restrict__ nanCnt)
{
    constexpr int NCOPY   = 4;
    constexpr int HSTRIDE = NBA + 1;
    __shared__ unsigned lh[NCOPY * HSTRIDE];      // 16.4 KB
    __shared__ unsigned bnan;
    const int tid   = threadIdx.x;
    const int wgid  = blockIdx.x;
    const int b     = wgid & 7;
    const int rest  = wgid >> 3;                  // 0..207
    const int w     = rest / CHUNKS;
    const int chunk = rest - w * CHUNKS;
    const int job   = b * W + w;
    unsigned* lhc = lh + ((tid >> 4) & (NCOPY - 1)) * HSTRIDE;

    for (int i = tid; i < NCOPY * HSTRIDE; i += 256) lh[i] = 0;
    if (tid == 0) bnan = 0;
    __syncthreads();

    unsigned localnan = 0;
    const float2* mrow = mixN + (size_t)b * TM * NBIN;
    const float2* arow = auxN + ((size_t)b * TROWS + (size_t)w * HS) * NBIN;

    const int pad = b & 1;                        // both bases share parity -> float4-aligned
    const int lim = pad + ((NVAL - pad) & ~1);

    for (int i = pad + (chunk * 256 + tid) * 2; i < lim; i += CHUNKS * 512) {
        float4 mv = *reinterpret_cast<const float4*>(mrow + i);
        float4 av = *reinterpret_cast<const float4*>(arow + i);
        float s0 = fmaf(mv.x, av.x, mv.y * av.y);
        float s1 = fmaf(mv.z, av.z, mv.w * av.w);
        if (!(s0 == s0)) localnan++;
        if (!(s1 == s1)) localnan++;
        atomicAdd(&lhc[qbin(s0)], 1u);
        atomicAdd(&lhc[qbin(s1)], 1u);
    }
    if (chunk == 0 && tid == 0) {                 // the one leftover scalar element
        int ie = pad ? 0 : NVAL - 1;
        float2 m = mrow[ie];
        float2 a = arow[ie];
        float s = fmaf(m.x, a.x, m.y * a.y);
        if (!(s == s)) localnan++;
        atomicAdd(&lhc[qbin(s)], 1u);
    }
    if (localnan) atomicAdd(&bnan, localnan);
    __syncthreads();

    unsigned* gh = hist + ((size_t)job * CHUNKS + chunk) * NBA;
    for (int i = tid; i < NBA; i += 256)
        gh[i] = lh[i] + lh[HSTRIDE + i] + lh[2 * HSTRIDE + i] + lh[3 * HSTRIDE + i];
    if (tid == 0) nanCnt[job * CHUNKS + chunk] = bnan;   // plain store
}

// ---------------- PASS B: inline scan (stateless) + compact selected-bin keys ----------
// Grid: 1D 1664, wgid%8 = batch (XCD pinning; re-reads come from this XCD's L2)
__global__ void sim_compact(const float2* __restrict__ mixN, const float2* __restrict__ auxN,
                            const unsigned* __restrict__ hist, unsigned* __restrict__ cand,
                            unsigned* __restrict__ ncand, unsigned* __restrict__ krem)
{
    const int tid   = threadIdx.x;
    const int wgid  = blockIdx.x;
    const int b     = wgid & 7;
    const int rest  = wgid >> 3;
    const int w     = rest / CHUNKS;
    const int chunk = rest - w * CHUNKS;
    const int job   = b * W + w;

    // every block recomputes the same {selbin, rem} from the global hist
    unsigned bins[NBA / 256];
    const unsigned* h = hist + (size_t)job * CHUNKS * NBA;
    #pragma unroll
    for (int i = 0; i < NBA / 256; ++i) {
        unsigned v = 0;
        int bin = tid * (NBA / 256) + i;
        #pragma unroll
        for (int c = 0; c < CHUNKS; ++c) v += h[(size_t)c * NBA + bin];
        bins[i] = v;
    }
    unsigned sb, rem;
    rank_find<NBA / 256>(bins, (unsigned)KMED, sb, rem);
    if (chunk == 0 && tid == 0) krem[job] = rem;

    unsigned* candj  = cand + (size_t)job * NVAL;
    unsigned* ncandj = ncand + job;
    const int lane = tid & 63;

    const float2* mrow = mixN + (size_t)b * TM * NBIN;
    const float2* arow = auxN + ((size_t)b * TROWS + (size_t)w * HS) * NBIN;

    const int pad = b & 1;
    const int lim = pad + ((NVAL - pad) & ~1);

    for (int i = pad + (chunk * 256 + tid) * 2; i < lim; i += CHUNKS * 512) {
        float4 mv = *reinterpret_cast<const float4*>(mrow + i);
        float4 av = *reinterpret_cast<const float4*>(arow + i);
        float sv[2];
        sv[0] = fmaf(mv.x, av.x, mv.y * av.y);
        sv[1] = fmaf(mv.z, av.z, mv.w * av.w);
        #pragma unroll
        for (int u = 0; u < 2; ++u) {
            bool pred = (qbin(sv[u]) == sb);
            unsigned long long m = __ballot(pred);
            if (m) {
                int leader = __ffsll(m) - 1;
                unsigned base = 0;
                if (lane == leader) base = atomicAdd(ncandj, (unsigned)__popcll(m));
                base = (unsigned)__shfl((int)base, leader);
                if (pred) candj[base + __popcll(m & ((1ull << lane) - 1ull))] = flip_key(sv[u]);
            }
        }
    }
    if (chunk == 0 && tid == 0) {
        int ie = pad ? 0 : NVAL - 1;
        float2 m = mrow[ie];
        float2 a = arow[ie];
        float s = fmaf(m.x, a.x, m.y * a.y);
        if (qbin(s) == sb) {
            unsigned idx = atomicAdd(ncandj, 1u);
            candj[idx] = flip_key(s);
        }
    }
}

// ---------------- exact rank-select among candidates (3-phase radix, parallel scan) -----
// Grid: 1D 208, wgid%8 = batch (same XCD as cand producer)
__global__ void select_kernel(const unsigned* __restrict__ cand, const unsigned* __restrict__ ncand,
                              const unsigned* __restrict__ krem, const unsigned* __restrict__ nanCnt,
                              float* __restrict__ med)
{
    __shared__ unsigned h[2048];
    const int wgid = blockIdx.x;
    const int job  = (wgid & 7) * W + (wgid >> 3);
    const int tid  = threadIdx.x;
    const unsigned* c = cand + (size_t)job * NVAL;
    const unsigned n = ncand[job];
    unsigned pref = 0, tgt = krem[job];

    for (int ph = 0; ph < 3; ++ph) {
        for (int i = tid; i < 2048; i += 256) h[i] = 0;
        __syncthreads();
        for (unsigned i = tid; i < n; i += 256) {
            unsigned k = c[i];
            if (ph == 0) atomicAdd(&h[k >> 21], 1u);
            else if (ph == 1) { if ((k >> 21) == (pref >> 21)) atomicAdd(&h[(k >> 10) & 2047u], 1u); }
            else { if ((k >> 10) == (pref >> 10)) atomicAdd(&h[k & 1023u], 1u); }
        }
        __syncthreads();

        unsigned bins[8];
        #pragma unroll
        for (int i = 0; i < 8; ++i) bins[i] = h[tid * 8 + i];
        unsigned sb, rem;
        rank_find<8>(bins, tgt, sb, rem);

        if (ph == 0)      pref = sb << 21;
        else if (ph == 1) pref |= sb << 10;
        else              pref |= sb;
        tgt = rem;
        __syncthreads();
    }

    if (tid == 0) {
        unsigned nan = 0;
        #pragma unroll
        for (int c2 = 0; c2 < CHUNKS; ++c2) nan += nanCnt[job * CHUNKS + c2];
        unsigned key = pref;
        unsigned u = (key & 0x80000000u) ? (key ^ 0x80000000u) : ~key;
        med[job] = (nan > 0u) ? -INFINITY : __uint_as_float(u);
    }
}

// ---------------- gather: inline argmax + recompute raw STFT of selected window ---------
// Grid: 1D 2056, wgid%8 = batch
__global__ void gather_stft(const float* __restrict__ x, const float* __restrict__ med,
                            float* __restrict__ out)
{
    constexpr int NX = 64 * (GFPB - 1) + NFFT;
    __shared__ float  xs[NX];
    __shared__ float2 Yl[GFPB][16][16];
    __shared__ float2 cis16[16];
    __shared__ int sh_best;

    const int tid  = threadIdx.x;
    const int wgid = blockIdx.x;
    const int b    = wgid & 7;
    const int t0   = (wgid >> 3) * GFPB;        // output row base (0..1024)

    if (tid == 0) {                             // inline argmax (first-wins)
        float mx = -INFINITY; int bi = 0;
        for (int w = 0; w < W; ++w) {
            float v = med[b * W + w];
            if (v > mx) { mx = v; bi = w; }
        }
        sh_best = bi;
    }
    if (tid < 16) cis16[tid] = twiddle(16 * tid);
    __syncthreads();

    const int fr0 = sh_best * HS + t0;          // aux frame base

    for (int i = tid; i < NX; i += 256) {
        int j = fr0 * HOP + i - 128;
        if (j < 0) j = -j;
        if (j >= LAUX) j = 2 * LAUX - 2 - j;
        j = max(0, min(LAUX - 1, j));           // safety clamp
        xs[i] = x[(size_t)b * LAUX + j];
    }
    __syncthreads();

    const int n1 = (tid >> 4) & 15;
    const int r  = tid & 15;
    {
        float reA[GFPB], imA[GFPB];
        #pragma unroll
        for (int f = 0; f < GFPB; ++f) { reA[f] = 0.f; imA[f] = 0.f; }
        int idx = 0;
        #pragma unroll
        for (int n2 = 0; n2 < 16; ++n2) {
            float2 tv = cis16[idx];
            #pragma unroll
            for (int f = 0; f < GFPB; ++f) {
                float v = xs[f * HOP + n1 + 16 * n2];
                reA[f] = fmaf(v, tv.x, reA[f]);
                imA[f] = fmaf(v, tv.y, imA[f]);
            }
            idx = (idx + r) & 15;
        }
        #pragma unroll
        for (int f = 0; f < GFPB; ++f) Yl[f][n1][r] = make_float2(reA[f], imA[f]);
    }
    __syncthreads();

    // 2 register-recurrence chains (tasks tid, tid+256; 516 tasks total) + tail
    auto dotask = [&](int jj) {
        const int f = jj / NBIN, k = jj - f * NBIN;
        const int tt = t0 + f;
        if (tt >= TM) return;
        float ar = 0.f, ai = 0.f;
        if (fr0 + f < TA) {                     // padded rows are zero
            const float2 dk = twiddle(k);
            float tr = 1.f, ti = 0.f;
            #pragma unroll
            for (int s = 0; s < 16; ++s) {
                float2 y = Yl[f][s][k & 15];
                ar = fmaf(tr, y.x, ar); ar = fmaf(-ti, y.y, ar);
                ai = fmaf(tr, y.y, ai); ai = fmaf( ti, y.x, ai);
                float nr = tr * dk.x - ti * dk.y;
                ti = fmaf(tr, dk.y, ti * dk.x); tr = nr;
            }
        }
        size_t o = (size_t)tt * NBIN + k;
        out[(size_t)(b * 2 + 0) * NVAL + o] = ar;
        out[(size_t)(b * 2 + 1) * NVAL + o] = ai;
    };
    dotask(tid);
    dotask(tid + 256);
    if (tid < GFPB * NBIN - 512) dotask(512 + tid);
}

// ---------------- launch (5 graph nodes) ----------------
extern "C" void kernel_launch(void* const* d_in, const int* in_sizes, int n_in,
                              void* d_out, int out_size, void* d_ws, size_t ws_size,
                              hipStream_t stream)
{
    const float* mix = (const float*)d_in[0];
    const float* aux = (const float*)d_in[1];
    float* out = (float*)d_out;
    char* ws = (char*)d_ws;

    float2*   mixN = (float2*)(ws + MIXN_OFF);
    float2*   auxN = (float2*)(ws + AUXN_OFF);
    unsigned* hist = (unsigned*)(ws + HIST_OFF);
    unsigned* cand = (unsigned*)(ws + CAND_OFF);
    unsigned* nanC = (unsigned*)(ws + NAN_OFF);
    unsigned* ncand= (unsigned*)(ws + NCAND_OFF);
    unsigned* krem = (unsigned*)(ws + KREM_OFF);
    float*    med  = (float*)(ws + MED_OFF);

    stft_all<<<(MIXBLKS + AUXBLKS) * NB, 256, 0, stream>>>(mix, aux, mixN, auxN, ncand);
    sim_hist<<<NJOBS * CHUNKS, 256, 0, stream>>>(mixN, auxN, hist, nanC);
    sim_compact<<<NJOBS * CHUNKS, 256, 0, stream>>>(mixN, auxN, hist, cand, ncand, krem);
    select_kernel<<<NJOBS, 256, 0, stream>>>(cand, ncand, krem, nanC, med);
    gather_stft<<<GBLKS * NB, 256, 0, stream>>>(aux, med, out);
}